// Round 17
// baseline (67.702 us; speedup 1.0000x reference)
//
#include <hip/hip_runtime.h>
#include <hip/hip_bf16.h>
#include <stdint.h>

// out[b][co][y][x0] = sum_{ci,ky,kx} x[b][ci][(y+ky-3)%256][(x0+kx-3)%256] * d[b][co][ci][ky][kx]
// Per (b,y-tile) GEMM: tmp[u][n=co*8+kx] = sum_{ci,ky} X[ci][(y+ky-3)%256][u] * w[co][ci][ky][kx]
// epilogue: out[x0] = sum_kx tmp[(x0+kx-3)&255][co*8+kx].  MFMA 32x32x16 bf16 (verified r3-r6,r12).
// v13 = v9 (38.8us best) + T14 split staging done RIGHT (r11's failure re-diagnosed as an
// epilogue aliasing bug -- its tmp dump lacked the leading barrier -- plus reg knife-edge;
// the T14 mechanism itself was never tested). Per chunk: issue 4 ci-loads -> compute ks0-1
// -> wait+cvt+write -> issue 4 -> compute ks2-3 -> write. Held regs per half = 16 VGPR
// (peak ~110 < 128 cap at launch_bounds(1024,4)). Writes to opposite buffer (r5-proven
// disjointness); epilogue byte-identical to v9 (barrier-first).

constexpr int NB = 8, CIN = 64, HH = 256, WW = 256, CO = 3, KK = 7;
constexpr int R = 8;             // output rows per block
constexpr int XROWS = 14;        // staged rows r=0..13 (input y0-3 .. y0+10)
constexpr int CI_CHUNK = 8;
constexpr int NCH = CIN / CI_CHUNK;
constexpr int XBUF = XROWS * 256 * 8;    // u16 elements per X buffer (28672)

typedef short bf16x8 __attribute__((ext_vector_type(8)));
typedef float f32x16 __attribute__((ext_vector_type(16)));

__device__ inline uint16_t f2bf(float f) {
    union { __hip_bfloat16 h; uint16_t u; } cv;
    cv.h = __float2bfloat16(f);          // HW RNE convert
    return cv.u;
}
// involution on 0..255 (16B-unit index): bits[3:0] ^= bits[7:4] (v9-validated)
__device__ inline int uswz(int u) { return u ^ ((u >> 4) & 15); }

// LDS: Xl[2][14][256][8] bf16 = 114688 B | Bl[32][64][8] bf16 = 32768 B  (147456 total)
// epilogue tmp f32[4][256][33] = 135168 B aliases Xl+Bl (after last compute).
__global__ __launch_bounds__(1024, 4)
void conv_mfma_v13(const float* __restrict__ x, const float* __restrict__ d,
                   float* __restrict__ outp) {
    __shared__ char smem[2 * XBUF * 2 + 32 * 64 * 8 * 2];
    uint16_t* Xl  = (uint16_t*)smem;
    uint16_t* Bl  = (uint16_t*)(smem + 2 * XBUF * 2);
    float*    tmp = (float*)smem;                      // [4][256][33]

    const int tid  = threadIdx.x;
    const int lane = tid & 63, wv = tid >> 6;          // 16 waves
    const int y_t  = wv >> 1, xh = wv & 1;
    const int l31  = lane & 31, lh = lane >> 5;

    // XCD swizzle: XCD (blk%8) owns image b; its 32 blocks cover adjacent y-tiles.
    const int blk = blockIdx.x;
    const int b   = blk & 7;
    const int y0  = (blk >> 3) * R;

    const float* xb = x + (size_t)b * CIN * HH * WW;
    const float* db = d + (size_t)b * CO * CIN * KK * KK;

    f32x16 acc[4];
    #pragma unroll
    for (int m = 0; m < 4; ++m)
        #pragma unroll
        for (int i = 0; i < 16; ++i) acc[m][i] = 0.f;

    // ---- T14 split staging: half h = ci (h*4 .. h*4+3) of chunk c ----
    auto issueHalf = [&](int c, int h, float4 (&v)[4]) {
        if (tid < XROWS * 64) {                        // 896 active threads
            const int r = tid >> 6, q = tid & 63;
            const int row = (y0 + r - 3) & (HH - 1);
            const float* p = xb + ((size_t)(c * CI_CHUNK + h * 4) * HH + row) * WW + q * 4;
            #pragma unroll
            for (int j = 0; j < 4; ++j)
                v[j] = *reinterpret_cast<const float4*>(p + (size_t)j * HH * WW);
        }
    };
    auto writeHalf = [&](int buf, int h, const float4 (&v)[4]) {
        if (tid < XROWS * 64) {
            const int r = tid >> 6, q = tid & 63;
            uint16_t* dst = Xl + (size_t)buf * XBUF + (size_t)r * 256 * 8 + h * 4;
            #pragma unroll
            for (int t = 0; t < 4; ++t) {
                uint2 pk;
                pk.x = (uint32_t)f2bf(((const float*)&v[0])[t]) | ((uint32_t)f2bf(((const float*)&v[1])[t]) << 16);
                pk.y = (uint32_t)f2bf(((const float*)&v[2])[t]) | ((uint32_t)f2bf(((const float*)&v[3])[t]) << 16);
                const int us = uswz(q * 4 + t);
                *reinterpret_cast<uint2*>(dst + (size_t)us * 8) = pk;
            }
        }
    };

    // ---- compute half: ks in {2h, 2h+1} (v9-verified mapping) ----
    auto computeHalf = [&](int c, int buf, int h) {
        const uint16_t* Xb = Xl + (size_t)buf * XBUF;
        #pragma unroll
        for (int ks = 2 * h; ks < 2 * h + 2; ++ks) {
            const int ky = ks * 2 + lh;
            int r = y_t + ky;                          // <= 14
            if (r >= XROWS) r = 0;                     // only y_t=7,ky=7 (zero weight)
            const int fi = c * 4 + ks;
            const bf16x8 bfrag = *reinterpret_cast<const bf16x8*>(&Bl[(size_t)(fi * 64 + lane) * 8]);
            #pragma unroll
            for (int m = 0; m < 4; ++m) {
                const int us = uswz(xh * 128 + m * 32 + l31);
                const bf16x8 afrag = *reinterpret_cast<const bf16x8*>(&Xb[((size_t)r * 256 + us) * 8]);
                acc[m] = __builtin_amdgcn_mfma_f32_32x32x16_bf16(afrag, bfrag, acc[m], 0, 0, 0);
            }
        }
    };

    // ---- prologue: X chunk 0 (both halves) + ALL of B (32 frags) ----
    {
        float4 v0[4], v1[4];
        issueHalf(0, 0, v0);
        issueHalf(0, 1, v1);
        #pragma unroll
        for (int q2 = 0; q2 < 2; ++q2) {
            const int s = tid + q2 * 1024;             // 2048 slots
            const int fi = s >> 6, ln = s & 63;
            const int cc8 = fi >> 2, ks = fi & 3;
            const int h = ln >> 5, n = ln & 31;
            const int ky = ks * 2 + h, co = n >> 3, kx = n & 7;
            uint16_t vals[8];
            #pragma unroll
            for (int j = 0; j < 8; ++j) {
                float v = 0.f;
                if (co < CO && kx < KK && ky < KK)
                    v = db[((size_t)co * CIN + cc8 * 8 + j) * (KK * KK) + ky * KK + kx];
                vals[j] = f2bf(v);
            }
            uint4 pk;
            pk.x = (uint32_t)vals[0] | ((uint32_t)vals[1] << 16);
            pk.y = (uint32_t)vals[2] | ((uint32_t)vals[3] << 16);
            pk.z = (uint32_t)vals[4] | ((uint32_t)vals[5] << 16);
            pk.w = (uint32_t)vals[6] | ((uint32_t)vals[7] << 16);
            *reinterpret_cast<uint4*>(&Bl[(size_t)(fi * 64 + ln) * 8]) = pk;
        }
        writeHalf(0, 0, v0);
        writeHalf(0, 1, v1);
    }

    // ---- main loop: barrier ; {issueA, computeH1, writeA, issueB, computeH2, writeB} ----
    for (int c = 0; c < NCH; ++c) {
        __syncthreads();                               // stage(c) writes visible
        const int buf = c & 1, nb2 = (c + 1) & 1;
        const bool pre = (c + 1 < NCH);
        float4 va[4], vb[4];
        if (pre) issueHalf(c + 1, 0, va);              // loads fly under computeH1
        computeHalf(c, buf, 0);
        if (pre) writeHalf(nb2, 0, va);                // opposite buffer: disjoint
        if (pre) issueHalf(c + 1, 1, vb);              // loads fly under computeH2
        computeHalf(c, buf, 1);
        if (pre) writeHalf(nb2, 1, vb);
    }

    // ---- epilogue (v9 byte-identical): 2 passes x 4 rows; tmp[4][256][33] aliases ----
    for (int p = 0; p < 2; ++p) {
        __syncthreads();                               // prior compute/reduce reads done
        if ((y_t >> 2) == p) {
            const int rr = y_t & 3;
            #pragma unroll
            for (int m = 0; m < 4; ++m)
                #pragma unroll
                for (int reg = 0; reg < 16; ++reg) {
                    const int rowloc = (reg & 3) + 8 * (reg >> 2) + 4 * lh;
                    const int u = xh * 128 + m * 32 + rowloc;
                    tmp[((size_t)rr * 256 + u) * 33 + l31] = acc[m][reg];
                }
        }
        __syncthreads();
        #pragma unroll
        for (int it0 = 0; it0 < 3; ++it0) {
            const int it = tid + it0 * 1024;
            if (it < 4 * CO * 256) {                   // 3072 items
                const int rr  = it / (CO * 256);
                const int rem = it - rr * (CO * 256);
                const int co  = rem >> 8, x0 = rem & 255;
                float s = 0.f;
                #pragma unroll
                for (int kx = 0; kx < 7; ++kx)
                    s += tmp[((size_t)rr * 256 + ((x0 + kx - 3) & 255)) * 33 + co * 8 + kx];
                outp[(((size_t)b * CO + co) * HH + (y0 + p * 4 + rr)) * WW + x0] = s;
            }
        }
    }
}

extern "C" void kernel_launch(void* const* d_in, const int* in_sizes, int n_in,
                              void* d_out, int out_size, void* d_ws, size_t ws_size,
                              hipStream_t stream) {
    const float* x = (const float*)d_in[0];
    const float* d = (const float*)d_in[1];
    float* outp = (float*)d_out;
    conv_mfma_v13<<<dim3(NB * (HH / R)), 1024, 0, stream>>>(x, d, outp);
}

// Round 18
// 39.054 us; speedup vs baseline: 1.7335x; 1.7335x over previous
//
#include <hip/hip_runtime.h>
#include <hip/hip_bf16.h>
#include <stdint.h>

// FINAL (revert to round-13 v9, session best 38.8us).
// out[b][co][y][x0] = sum_{ci,ky,kx} x[b][ci][(y+ky-3)%256][(x0+kx-3)%256] * d[b][co][ci][ky][kx]
// Per (b,y-tile) GEMM: tmp[u][n=co*8+kx] = sum_{ci,ky} X[ci][(y+ky-3)%256][u] * w[co][ci][ky][kx]
// epilogue: out[x0] = sum_kx tmp[(x0+kx-3)&255][co*8+kx].  MFMA 32x32x16 bf16 (verified r3-r6,r12).
//   1. full 4-bit unit swizzle u^=(u>>4)&15: staging ds_write_b128 covers all 8 bank groups
//      (killed the 2.75M SQ_LDS_BANK_CONFLICT measured in r10); frag reads broadcast-free.
//   2. epilogue 2 passes x 4 rows (tmp[4][256][33] aliases Xl+Bl after last compute).
// Session post-mortem: 7 structural alternatives (demand reduction x2, register tiling,
// barrier decorrelation, occupancy, producer/consumer, register-held async staging x3)
// all regressed or spilled; ~39us is this formulation's phase-serialization floor
// (r10/r16 PMC: input L3-resident, no pipe >21%, latency-bound at the barrier drain).

constexpr int NB = 8, CIN = 64, HH = 256, WW = 256, CO = 3, KK = 7;
constexpr int R = 8;             // output rows per block
constexpr int XROWS = 14;        // staged rows r=0..13 (input y0-3 .. y0+10)
constexpr int CI_CHUNK = 8;
constexpr int NCH = CIN / CI_CHUNK;
constexpr int XBUF = XROWS * 256 * 8;    // u16 elements per X buffer (28672)

typedef short bf16x8 __attribute__((ext_vector_type(8)));
typedef float f32x16 __attribute__((ext_vector_type(16)));

__device__ inline uint16_t f2bf(float f) {
    union { __hip_bfloat16 h; uint16_t u; } cv;
    cv.h = __float2bfloat16(f);          // HW RNE convert
    return cv.u;
}
// involution on 0..255 (16B-unit index): bits[3:0] ^= bits[7:4].
__device__ inline int uswz(int u) { return u ^ ((u >> 4) & 15); }

// LDS: Xl[2][14][256][8] bf16 = 114688 B | Bl[32][64][8] bf16 = 32768 B  (147456 total)
// epilogue tmp f32[4][256][33] = 135168 B aliases Xl+Bl (after last compute).
__global__ __launch_bounds__(1024, 4)
void conv_mfma_v9(const float* __restrict__ x, const float* __restrict__ d,
                  float* __restrict__ outp) {
    __shared__ char smem[2 * XBUF * 2 + 32 * 64 * 8 * 2];
    uint16_t* Xl  = (uint16_t*)smem;
    uint16_t* Bl  = (uint16_t*)(smem + 2 * XBUF * 2);
    float*    tmp = (float*)smem;                      // [4][256][33]

    const int tid  = threadIdx.x;
    const int lane = tid & 63, wv = tid >> 6;          // 16 waves
    const int y_t  = wv >> 1, xh = wv & 1;
    const int l31  = lane & 31, lh = lane >> 5;

    // XCD swizzle: XCD (blk%8) owns image b; its 32 blocks cover adjacent y-tiles.
    const int blk = blockIdx.x;
    const int b   = blk & 7;
    const int y0  = (blk >> 3) * R;

    const float* xb = x + (size_t)b * CIN * HH * WW;
    const float* db = d + (size_t)b * CO * CIN * KK * KK;

    f32x16 acc[4];
    #pragma unroll
    for (int m = 0; m < 4; ++m)
        #pragma unroll
        for (int i = 0; i < 16; ++i) acc[m][i] = 0.f;

    // ---- stage chunk c of X into buffer `buf` (unified r5-proven phase) ----
    auto stageX = [&](int c, int buf) {
        if (tid < XROWS * 64) {                        // 896 active threads
            const int r = tid >> 6, q = tid & 63;
            const int row = (y0 + r - 3) & (HH - 1);
            const float* p = xb + ((size_t)(c * CI_CHUNK) * HH + row) * WW + q * 4;
            float4 v[8];
            #pragma unroll
            for (int j = 0; j < 8; ++j)
                v[j] = *reinterpret_cast<const float4*>(p + (size_t)j * HH * WW);
            uint16_t* dst = Xl + (size_t)buf * XBUF + (size_t)r * 256 * 8;
            #pragma unroll
            for (int t = 0; t < 4; ++t) {
                uint4 pk;
                pk.x = (uint32_t)f2bf(((const float*)&v[0])[t]) | ((uint32_t)f2bf(((const float*)&v[1])[t]) << 16);
                pk.y = (uint32_t)f2bf(((const float*)&v[2])[t]) | ((uint32_t)f2bf(((const float*)&v[3])[t]) << 16);
                pk.z = (uint32_t)f2bf(((const float*)&v[4])[t]) | ((uint32_t)f2bf(((const float*)&v[5])[t]) << 16);
                pk.w = (uint32_t)f2bf(((const float*)&v[6])[t]) | ((uint32_t)f2bf(((const float*)&v[7])[t]) << 16);
                const int us = uswz(q * 4 + t);        // full 8-group spread
                *reinterpret_cast<uint4*>(dst + (size_t)us * 8) = pk;
            }
        }
    };

    // ---- compute chunk c from buffer `buf` ----
    auto compute = [&](int c, int buf) {
        const uint16_t* Xb = Xl + (size_t)buf * XBUF;
        #pragma unroll
        for (int ks = 0; ks < 4; ++ks) {
            const int ky = ks * 2 + lh;
            int r = y_t + ky;                          // <= 14
            if (r >= XROWS) r = 0;                     // only y_t=7,ky=7 (zero weight)
            const int fi = c * 4 + ks;
            const bf16x8 bfrag = *reinterpret_cast<const bf16x8*>(&Bl[(size_t)(fi * 64 + lane) * 8]);
            #pragma unroll
            for (int m = 0; m < 4; ++m) {
                const int us = uswz(xh * 128 + m * 32 + l31);
                const bf16x8 afrag = *reinterpret_cast<const bf16x8*>(&Xb[((size_t)r * 256 + us) * 8]);
                acc[m] = __builtin_amdgcn_mfma_f32_32x32x16_bf16(afrag, bfrag, acc[m], 0, 0, 0);
            }
        }
    };

    // ---- prologue: X chunk 0 + ALL of B (32 frags, fragment order) ----
    stageX(0, 0);
    #pragma unroll
    for (int q2 = 0; q2 < 2; ++q2) {
        const int s = tid + q2 * 1024;                 // 2048 slots
        const int fi = s >> 6, ln = s & 63;
        const int cc8 = fi >> 2, ks = fi & 3;
        const int h = ln >> 5, n = ln & 31;
        const int ky = ks * 2 + h, co = n >> 3, kx = n & 7;
        uint16_t vals[8];
        #pragma unroll
        for (int j = 0; j < 8; ++j) {
            float v = 0.f;
            if (co < CO && kx < KK && ky < KK)
                v = db[((size_t)co * CIN + cc8 * 8 + j) * (KK * KK) + ky * KK + kx];
            vals[j] = f2bf(v);
        }
        uint4 pk;
        pk.x = (uint32_t)vals[0] | ((uint32_t)vals[1] << 16);
        pk.y = (uint32_t)vals[2] | ((uint32_t)vals[3] << 16);
        pk.z = (uint32_t)vals[4] | ((uint32_t)vals[5] << 16);
        pk.w = (uint32_t)vals[6] | ((uint32_t)vals[7] << 16);
        *reinterpret_cast<uint4*>(&Bl[(size_t)(fi * 64 + ln) * 8]) = pk;
    }

    // ---- main loop (r5-proven): barrier ; stage(c+1) ; compute(c) ----
    for (int c = 0; c < NCH; ++c) {
        __syncthreads();                               // buf[c&1] writes visible
        if (c + 1 < NCH) stageX(c + 1, (c + 1) & 1);   // writes opposite buffer
        compute(c, c & 1);
    }

    // ---- epilogue: 2 passes x 4 rows; tmp[4][256][33] aliases Xl+Bl ----
    for (int p = 0; p < 2; ++p) {
        __syncthreads();                               // prior compute/reduce reads done
        if ((y_t >> 2) == p) {
            const int rr = y_t & 3;
            #pragma unroll
            for (int m = 0; m < 4; ++m)
                #pragma unroll
                for (int reg = 0; reg < 16; ++reg) {
                    const int rowloc = (reg & 3) + 8 * (reg >> 2) + 4 * lh;
                    const int u = xh * 128 + m * 32 + rowloc;
                    tmp[((size_t)rr * 256 + u) * 33 + l31] = acc[m][reg];
                }
        }
        __syncthreads();
        #pragma unroll
        for (int it0 = 0; it0 < 3; ++it0) {
            const int it = tid + it0 * 1024;
            if (it < 4 * CO * 256) {                   // 3072 items
                const int rr  = it / (CO * 256);
                const int rem = it - rr * (CO * 256);
                const int co  = rem >> 8, x0 = rem & 255;
                float s = 0.f;
                #pragma unroll
                for (int kx = 0; kx < 7; ++kx)
                    s += tmp[((size_t)rr * 256 + ((x0 + kx - 3) & 255)) * 33 + co * 8 + kx];
                outp[(((size_t)b * CO + co) * HH + (y0 + p * 4 + rr)) * WW + x0] = s;
            }
        }
    }
}

extern "C" void kernel_launch(void* const* d_in, const int* in_sizes, int n_in,
                              void* d_out, int out_size, void* d_ws, size_t ws_size,
                              hipStream_t stream) {
    const float* x = (const float*)d_in[0];
    const float* d = (const float*)d_in[1];
    float* outp = (float*)d_out;
    conv_mfma_v9<<<dim3(NB * (HH / R)), 1024, 0, stream>>>(x, d, outp);
}